// Round 1
// baseline (169.963 us; speedup 1.0000x reference)
//
#include <hip/hip_runtime.h>
#include <hip/hip_bf16.h>
#include <math.h>

// TopicRouter: logits = h @ gate_w^T + gate_b; top-2; softmax(top vals).
// B=32768, D=768, E=8, TOP_K=2. All f32. Memory-bound on reading h (96 MB).
//
// Mapping: one wave processes 2 rows per iteration.
//  - h row = 192 float4; lane reads float4 at {lane, lane+64, lane+128}.
//  - gate_w (8x768 f32 = 24 KB) staged in LDS once per block; ds_read_b128.
//  - per-lane acc[8] (one per expert) reduced across the wave with a
//    transpose-butterfly: 3 halving steps (xor 1,2,4) leave 1 value/lane
//    (expert = bitrev3(lane&7)), then 3 plain xor-add steps (8,16,32).
//  - 8-shuffle gather into expert order, branchless stable top-2
//    (strict > == lax.top_k lowest-index-first tie-break), exact softmax.

constexpr int D  = 768;
constexpr int E  = 8;
constexpr int D4 = D / 4;          // 192 float4 per row
constexpr int BLOCK = 256;         // 4 waves
constexpr int GRID  = 1024;        // 4096 waves -> 4 row-pairs per wave

__device__ __forceinline__ float dot4acc(float4 a, float4 b, float acc) {
    acc = fmaf(a.x, b.x, acc);
    acc = fmaf(a.y, b.y, acc);
    acc = fmaf(a.z, b.z, acc);
    acc = fmaf(a.w, b.w, acc);
    return acc;
}

// Reduce a[8] (per-expert partials) across 64 lanes.
// Returns: this lane's total for expert e = bitrev3(lane&7).
__device__ __forceinline__ float wave_reduce8(float a[8], int lane) {
    {   // xor 1: keep 4 values
        const bool hi = lane & 1;
#pragma unroll
        for (int j = 0; j < 4; ++j) {
            float send = hi ? a[j] : a[j + 4];
            float recv = __shfl_xor(send, 1, 64);
            float keep = hi ? a[j + 4] : a[j];
            a[j] = keep + recv;
        }
    }
    {   // xor 2: keep 2 values
        const bool hi = lane & 2;
#pragma unroll
        for (int j = 0; j < 2; ++j) {
            float send = hi ? a[j] : a[j + 2];
            float recv = __shfl_xor(send, 2, 64);
            float keep = hi ? a[j + 2] : a[j];
            a[j] = keep + recv;
        }
    }
    {   // xor 4: keep 1 value
        const bool hi = lane & 4;
        float send = hi ? a[0] : a[1];
        float recv = __shfl_xor(send, 4, 64);
        float keep = hi ? a[1] : a[0];
        a[0] = keep + recv;
    }
    float v = a[0];
    v += __shfl_xor(v, 8, 64);
    v += __shfl_xor(v, 16, 64);
    v += __shfl_xor(v, 32, 64);
    return v;
}

__device__ __forceinline__ void finalize_row(
        float v /* reduced, bias already added */, int lane, int obase,
        int e_lane, int row,
        float* __restrict__ out_idx, float* __restrict__ out_w,
        float* __restrict__ out_logits) {
    // Gather the octet's 8 logits into expert order. Lane holding expert k
    // within an octet is bitrev3(k): 0,4,2,6,1,5,3,7.
    float l[8];
    l[0] = __shfl(v, obase | 0, 64);
    l[1] = __shfl(v, obase | 4, 64);
    l[2] = __shfl(v, obase | 2, 64);
    l[3] = __shfl(v, obase | 6, 64);
    l[4] = __shfl(v, obase | 1, 64);
    l[5] = __shfl(v, obase | 5, 64);
    l[6] = __shfl(v, obase | 3, 64);
    l[7] = __shfl(v, obase | 7, 64);

    // Stable top-2 (strict >): ties keep the lower expert index, matching
    // jax.lax.top_k.
    float v0 = l[0]; int i0 = 0;
    float v1 = -INFINITY; int i1 = -1;
#pragma unroll
    for (int e = 1; e < 8; ++e) {
        float x = l[e];
        bool gt0 = x > v0;
        bool gt1 = x > v1;
        float nv1 = gt0 ? v0 : (gt1 ? x : v1);
        int   ni1 = gt0 ? i0 : (gt1 ? e : i1);
        v1 = nv1; i1 = ni1;
        v0 = gt0 ? x : v0;
        i0 = gt0 ? e : i0;
    }
    // softmax over [v0, v1], v0 >= v1
    float t = expf(v1 - v0);
    float w0 = 1.0f / (1.0f + t);
    float w1 = t * w0;

    if (lane < 2) {
        out_idx[row * 2 + lane] = (float)(lane ? i1 : i0);
        out_w  [row * 2 + lane] = lane ? w1 : w0;
    }
    if (lane < 8) {
        out_logits[row * 8 + e_lane] = v;   // e_lane distinct over lanes 0..7
    }
}

__global__ __launch_bounds__(BLOCK, 4)
void topic_router_kernel(const float* __restrict__ h,
                         const float* __restrict__ gate_w,
                         const float* __restrict__ gate_b,
                         float* __restrict__ out_idx,
                         float* __restrict__ out_w,
                         float* __restrict__ out_logits,
                         int B) {
    __shared__ float gate_s[E * D];

    const int tid = threadIdx.x;
    const float4* gw4 = (const float4*)gate_w;
    float4* gs4 = (float4*)gate_s;
#pragma unroll
    for (int i = tid; i < E * D4; i += BLOCK) gs4[i] = gw4[i];
    __syncthreads();

    const int lane  = tid & 63;
    const int wave  = tid >> 6;
    const int gwave = blockIdx.x * (BLOCK / 64) + wave;
    const int nwaves = gridDim.x * (BLOCK / 64);

    const int l3 = lane & 7;
    const int e_lane = ((l3 & 1) << 2) | (l3 & 2) | ((l3 >> 2) & 1);
    const float bias = gate_b[e_lane];
    const int obase = lane & 56;

    const float4* h4 = (const float4*)h;
    const int npairs = B >> 1;

    for (int p = gwave; p < npairs; p += nwaves) {
        const int r0 = p * 2;
        const float4* hp0 = h4 + (size_t)r0 * D4 + lane;
        const float4* hp1 = hp0 + D4;

        // Issue all 6 global loads up front (latency hiding).
        float4 hv0[3], hv1[3];
#pragma unroll
        for (int c = 0; c < 3; ++c) hv0[c] = hp0[c * 64];
#pragma unroll
        for (int c = 0; c < 3; ++c) hv1[c] = hp1[c * 64];

        float acc0[E], acc1[E];
#pragma unroll
        for (int e = 0; e < E; ++e) { acc0[e] = 0.0f; acc1[e] = 0.0f; }

#pragma unroll
        for (int c = 0; c < 3; ++c) {
#pragma unroll
            for (int e = 0; e < E; ++e) {
                float4 g = gs4[e * D4 + c * 64 + lane];
                acc0[e] = dot4acc(hv0[c], g, acc0[e]);
                acc1[e] = dot4acc(hv1[c], g, acc1[e]);
            }
        }

        float va = wave_reduce8(acc0, lane) + bias;
        float vb = wave_reduce8(acc1, lane) + bias;
        finalize_row(va, lane, obase, e_lane, r0,     out_idx, out_w, out_logits);
        finalize_row(vb, lane, obase, e_lane, r0 + 1, out_idx, out_w, out_logits);
    }
}

extern "C" void kernel_launch(void* const* d_in, const int* in_sizes, int n_in,
                              void* d_out, int out_size, void* d_ws, size_t ws_size,
                              hipStream_t stream) {
    const float* h      = (const float*)d_in[0];
    const float* gate_w = (const float*)d_in[1];
    const float* gate_b = (const float*)d_in[2];

    const int B = in_sizes[0] / D;   // 32768

    float* out        = (float*)d_out;
    float* out_idx    = out;                       // [B,2] indices as float
    float* out_w      = out + (size_t)B * 2;       // [B,2] weights
    float* out_logits = out + (size_t)B * 4;       // [B,8] logits

    topic_router_kernel<<<dim3(GRID), dim3(BLOCK), 0, stream>>>(
        h, gate_w, gate_b, out_idx, out_w, out_logits, B);
}